// Round 7
// baseline (79.990 us; speedup 1.0000x reference)
//
#include <hip/hip_runtime.h>
#include <cstdint>
#include <cstddef>

// Problem constants: B=16, S=512, DEG=8, D=512, L=64
#define DDIM   512
#define NNODES 8192      // B*S
#define NEDGE  65536     // B*S*DEG
#define KDIM   1664      // 3*D + 2*L; 52 k-tiles of 32
#define NKT    52
#define TILE_SHORTS 4096 // one (128-row x 32-k) bf16 tile = [4 kb][128 row][8]

typedef __attribute__((ext_vector_type(8))) short bf16x8;
typedef __attribute__((ext_vector_type(4))) float f32x4;

#define AS1 __attribute__((address_space(1)))
#define AS3 __attribute__((address_space(3)))

static __device__ __forceinline__ unsigned short f2bf(float f) {
    unsigned u = __float_as_uint(f);
    u += 0x7FFFu + ((u >> 16) & 1u);   // round-to-nearest-even
    return (unsigned short)(u >> 16);
}

static __device__ __forceinline__ void unpack8(uint4 pv, float* pf) {
    const unsigned* pw = (const unsigned*)&pv;
    pf[0] = __uint_as_float(pw[0] << 16); pf[1] = __uint_as_float(pw[0] & 0xffff0000u);
    pf[2] = __uint_as_float(pw[1] << 16); pf[3] = __uint_as_float(pw[1] & 0xffff0000u);
    pf[4] = __uint_as_float(pw[2] << 16); pf[5] = __uint_as_float(pw[2] & 0xffff0000u);
    pf[6] = __uint_as_float(pw[3] << 16); pf[7] = __uint_as_float(pw[3] & 0xffff0000u);
}

// ---------------------------------------------------------------------------
// Kernel 1 (merged): blocks [0,2048): x->bf16 + gate dots.
//                    blocks [2048,2256): tiled-transposed bf16 weight build.
// B tiled layout: tile(tn,kt) at ((tn*52+kt)*4096) shorts, [kb][nrow][8].
// ---------------------------------------------------------------------------
__global__ __launch_bounds__(256) void prep_kernel(
    const float* __restrict__ src,
    const float* __restrict__ vg_in, const float* __restrict__ vg_out,
    const float* __restrict__ vg_loop,
    const float* __restrict__ v_in, const float* __restrict__ v_out,
    const float* __restrict__ w_loop, const float* __restrict__ b_in,
    const float* __restrict__ b_out,
    unsigned short* __restrict__ xb, unsigned short* __restrict__ wbt,
    float* __restrict__ g_in, float* __restrict__ g_out, float* __restrict__ g_loop)
{
    __shared__ float tile[64][65];
    if (blockIdx.x < 2048) {
        int lane = threadIdx.x & 63;
        int row  = blockIdx.x * 4 + (threadIdx.x >> 6);
        int j0   = lane * 8;

        const float* x = src + (size_t)row * DDIM + j0;
        float4 x0 = *(const float4*)x;
        float4 x1 = *(const float4*)(x + 4);
        float xs[8] = {x0.x, x0.y, x0.z, x0.w, x1.x, x1.y, x1.z, x1.w};

        alignas(16) unsigned short h[8];
#pragma unroll
        for (int i = 0; i < 8; ++i) h[i] = f2bf(xs[i]);
        *(uint4*)(xb + (size_t)row * DDIM + j0) = *(const uint4*)h;

        float s0 = 0.f, s1 = 0.f, s2 = 0.f;
#pragma unroll
        for (int i = 0; i < 8; ++i) {
            s0 += xs[i] * vg_in[j0 + i];
            s1 += xs[i] * vg_out[j0 + i];
            s2 += xs[i] * vg_loop[j0 + i];
        }
#pragma unroll
        for (int o = 32; o > 0; o >>= 1) {
            s0 += __shfl_xor(s0, o);
            s1 += __shfl_xor(s1, o);
            s2 += __shfl_xor(s2, o);
        }
        if (lane == 0) { g_in[row] = s0; g_out[row] = s1; g_loop[row] = s2; }
    } else {
        int bb = blockIdx.x - 2048;
        int ktb = bb / 8;             // 0..25 (64-k chunk)
        int nt  = bb % 8;             // 0..7 (64-wide n chunk)
        int k0 = ktb * 64, n0 = nt * 64;

        const float* srcp; int kbase;
        if      (ktb < 8)  { srcp = v_in;   kbase = 0; }
        else if (ktb < 16) { srcp = v_out;  kbase = 512; }
        else if (ktb < 24) { srcp = w_loop; kbase = 1024; }
        else if (ktb == 24){ srcp = b_in;   kbase = 1536; }
        else               { srcp = b_out;  kbase = 1600; }

        int c  = threadIdx.x & 63;
        int rr = threadIdx.x >> 6;    // 0..3
#pragma unroll
        for (int i = 0; i < 16; ++i) {
            int kk = i * 4 + rr;
            tile[kk][c] = srcp[(size_t)(k0 + kk - kbase) * DDIM + n0 + c];
        }
        __syncthreads();
        // write 512 chunks of 16B: idx = nn(0..63) x k8(0..7)
        int tn = nt >> 1;
        int nrbase = (nt & 1) * 64;
#pragma unroll
        for (int rep = 0; rep < 2; ++rep) {
            int idx = rep * 256 + threadIdx.x;   // 0..511
            int nn  = idx >> 3;
            int k8  = idx & 7;                   // 8-elem k-group within 64
            int ktl = k8 >> 2;                   // which 32-k tile (0/1)
            int kb  = k8 & 3;                    // kb within tile
            size_t tb = ((size_t)(tn * NKT + ktb * 2 + ktl)) * TILE_SHORTS;
            alignas(16) unsigned short h[8];
#pragma unroll
            for (int e = 0; e < 8; ++e) h[e] = f2bf(tile[k8 * 8 + e][nn]);
            *(uint4*)(wbt + tb + ((size_t)kb * 128 + nrbase + nn) * 8) = *(const uint4*)h;
        }
    }
}

// ---------------------------------------------------------------------------
// Kernel 2: gather-aggregate in x-space -> TILED A layout.
// tile(tm,kt) at ((tm*52+kt)*4096) shorts, [4 kb][128 row][8]; row = n&127.
// Lane j owns k-elems 8j..8j+7 -> kt = seg*16 + (lane>>2), kb = lane&3.
// 512-thread blocks / 8 consecutive nodes: the 8 rows sharing each 128B
// line of At are written by the SAME block -> full-line writes.
// ---------------------------------------------------------------------------
__global__ __launch_bounds__(512) void aggx_kernel(
    const unsigned short* __restrict__ xb,
    const float* __restrict__ g_in, const float* __restrict__ g_out,
    const float* __restrict__ g_loop,
    const int* __restrict__ arc_in, const int* __restrict__ lbl_in,
    const int* __restrict__ arc_out, const int* __restrict__ lbl_out,
    const float* __restrict__ mask_in, const float* __restrict__ mask_out,
    const float* __restrict__ mask_loop,
    const float* __restrict__ bg_in, const float* __restrict__ bg_out,
    unsigned short* __restrict__ A)
{
    int lane = threadIdx.x & 63;
    int n    = blockIdx.x * 8 + (threadIdx.x >> 6);
    int j0   = lane * 8;

    float acc_in[8] = {0,0,0,0,0,0,0,0};
    float acc_out[8] = {0,0,0,0,0,0,0,0};
    float hin = 0.f, hout = 0.f;

#pragma unroll
    for (int k = 0; k < 8; ++k) {
        int e  = n * 8 + k;                    // wave-uniform
        float mk = mask_in[e];
        if (mk != 0.f) {                        // wave-uniform branch
            int sn = arc_in[e] * 512 + arc_in[NEDGE + e];
            int lb = lbl_in[e];
            float w = mk / (1.0f + __expf(-(g_in[sn] + bg_in[lb])));
            uint4 pv = *(const uint4*)(xb + (size_t)sn * DDIM + j0);
            float pf[8]; unpack8(pv, pf);
#pragma unroll
            for (int i = 0; i < 8; ++i) acc_in[i] += w * pf[i];
            hin += (lb == lane) ? w : 0.f;
        }
    }
#pragma unroll
    for (int k = 0; k < 8; ++k) {
        int e  = n * 8 + k;
        float mk = mask_out[e];
        if (mk != 0.f) {
            int sn = arc_out[e] * 512 + arc_out[NEDGE + e];
            int lb = lbl_out[e];
            float w = mk / (1.0f + __expf(-(g_out[sn] + bg_out[lb])));
            uint4 pv = *(const uint4*)(xb + (size_t)sn * DDIM + j0);
            float pf[8]; unpack8(pv, pf);
#pragma unroll
            for (int i = 0; i < 8; ++i) acc_out[i] += w * pf[i];
            hout += (lb == lane) ? w : 0.f;
        }
    }
    float wl = mask_loop[n] / (1.0f + __expf(-g_loop[n]));
    uint4 own = *(const uint4*)(xb + (size_t)n * DDIM + j0);
    float lp[8]; unpack8(own, lp);

    int tm = n >> 7, rw = n & 127;
    int ktl = lane >> 2, kb = lane & 3;        // within 512-k segment
    size_t rowoff = ((size_t)kb * 128 + rw) * 8;
    size_t tmb = (size_t)tm * NKT * TILE_SHORTS;

    alignas(16) unsigned short h[8];
#pragma unroll
    for (int i = 0; i < 8; ++i) h[i] = f2bf(acc_in[i]);
    *(uint4*)(A + tmb + (size_t)ktl * TILE_SHORTS + rowoff) = *(const uint4*)h;
#pragma unroll
    for (int i = 0; i < 8; ++i) h[i] = f2bf(acc_out[i]);
    *(uint4*)(A + tmb + (size_t)(16 + ktl) * TILE_SHORTS + rowoff) = *(const uint4*)h;
#pragma unroll
    for (int i = 0; i < 8; ++i) h[i] = f2bf(wl * lp[i]);
    *(uint4*)(A + tmb + (size_t)(32 + ktl) * TILE_SHORTS + rowoff) = *(const uint4*)h;
    // histograms: k = 1536+lane -> kt 48 + (lane>>5); k = 1600+lane -> kt 50 + (lane>>5)
    {
        int kt_h = 48 + (lane >> 5);
        int kb_h = (lane & 31) >> 3;
        int el   = lane & 7;
        A[tmb + (size_t)kt_h * TILE_SHORTS + ((size_t)kb_h * 128 + rw) * 8 + el] = f2bf(hin);
        kt_h = 50 + (lane >> 5);
        A[tmb + (size_t)kt_h * TILE_SHORTS + ((size_t)kb_h * 128 + rw) * 8 + el] = f2bf(hout);
    }
}

// ---------------------------------------------------------------------------
// Kernel 3: GEMM  H[8192 x 512](bf16) = A[8192 x 1664] @ Wstack[1664 x 512]
// Pre-tiled operands (exact LDS image) -> fully coalesced staging.
// 128x128 tile, BK=32, 512 threads (8 waves 2m x 4n, each 64x32, 4x2 frags).
// Depth-4 LDS ring now 64 KB total -> 2 blocks/CU (TLP) AND lookahead-3
// counted vmcnt. 52 K-iterations. Grid 256, XCD-affine swizzle.
// ---------------------------------------------------------------------------
__global__ __launch_bounds__(512, 4) void gemm6_kernel(
    const unsigned short* __restrict__ At,
    const unsigned short* __restrict__ Bt,
    unsigned short* __restrict__ H)
{
    __shared__ short lds_a[4][TILE_SHORTS];   // 4 bufs x 8 KB = 32 KB
    __shared__ short lds_b[4][TILE_SHORTS];   // 32 KB

    int tid  = threadIdx.x;
    int lane = tid & 63;
    int wid  = tid >> 6;                    // 0..7
    int bid  = blockIdx.x;
    int local = bid >> 3;                   // 0..31
    int tm    = (bid & 7) * 8 + (local >> 2);
    int tn    = local & 3;
    int row0 = tm * 128, col0 = tn * 128;
    int wm   = wid >> 2, wn = wid & 3;      // 2m x 4n waves, each 64 x 32
    int r16  = lane & 15, kq = lane >> 4;

    f32x4 acc[4][2];
#pragma unroll
    for (int m = 0; m < 4; ++m)
#pragma unroll
        for (int n = 0; n < 2; ++n) acc[m][n] = (f32x4){0.f, 0.f, 0.f, 0.f};

    const unsigned short* ga = At + (size_t)(tm * NKT) * TILE_SHORTS;
    const unsigned short* gb = Bt + (size_t)(tn * NKT) * TILE_SHORTS;

    // Fully coalesced stage: thread tid copies 16B at tile offset tid*16.
    auto stage = [&](int buf, int kt) {
        size_t kt8 = (size_t)kt * TILE_SHORTS;
        __builtin_amdgcn_global_load_lds(
            (const AS1 void*)(ga + kt8 + tid * 8),
            (AS3 void*)(&lds_a[buf][wid * 512]), 16, 0, 0);
        __builtin_amdgcn_global_load_lds(
            (const AS1 void*)(gb + kt8 + tid * 8),
            (AS3 void*)(&lds_b[buf][wid * 512]), 16, 0, 0);
    };

    auto compute = [&](int buf) {
        const short* la = lds_a[buf];
        const short* lb = lds_b[buf];
        bf16x8 af[4], bfr[2];
#pragma unroll
        for (int m = 0; m < 4; ++m)
            af[m] = *(const bf16x8*)(la + (kq * 128 + wm * 64 + m * 16 + r16) * 8);
#pragma unroll
        for (int n = 0; n < 2; ++n)
            bfr[n] = *(const bf16x8*)(lb + (kq * 128 + wn * 32 + n * 16 + r16) * 8);
#pragma unroll
        for (int m = 0; m < 4; ++m)
#pragma unroll
            for (int n = 0; n < 2; ++n)
                acc[m][n] = __builtin_amdgcn_mfma_f32_16x16x32_bf16(
                    af[m], bfr[n], acc[m][n], 0, 0, 0);
        __builtin_amdgcn_sched_barrier(0);
        __builtin_amdgcn_s_barrier();           // release buffer for restaging
    };

    // prologue: 3 stages in flight (6 loads/thread)
    stage(0, 0); stage(1, 1); stage(2, 2);

    // main loop: t = 0..48 stages t+3 = 3..51
    for (int t = 0; t < 49; ++t) {
        stage((t + 3) & 3, t + 3);
        asm volatile("s_waitcnt vmcnt(6)" ::: "memory");   // stage t landed
        __builtin_amdgcn_sched_barrier(0);
        __builtin_amdgcn_s_barrier();
        __builtin_amdgcn_sched_barrier(0);
        compute(t & 3);
    }
    // epilogue: t = 49, 50, 51 (drain 4 -> 2 -> 0)
    asm volatile("s_waitcnt vmcnt(4)" ::: "memory");
    __builtin_amdgcn_sched_barrier(0);
    __builtin_amdgcn_s_barrier();
    __builtin_amdgcn_sched_barrier(0);
    compute(1);
    asm volatile("s_waitcnt vmcnt(2)" ::: "memory");
    __builtin_amdgcn_sched_barrier(0);
    __builtin_amdgcn_s_barrier();
    __builtin_amdgcn_sched_barrier(0);
    compute(2);
    asm volatile("s_waitcnt vmcnt(0)" ::: "memory");
    __builtin_amdgcn_sched_barrier(0);
    __builtin_amdgcn_s_barrier();
    __builtin_amdgcn_sched_barrier(0);
    compute(3);

    // C/D layout: col = lane&15, row = (lane>>4)*4 + reg; store bf16
#pragma unroll
    for (int m = 0; m < 4; ++m) {
        int grow = row0 + wm * 64 + m * 16 + kq * 4;
#pragma unroll
        for (int n = 0; n < 2; ++n) {
            int gcol = col0 + wn * 32 + n * 16 + r16;
#pragma unroll
            for (int r = 0; r < 4; ++r)
                H[(size_t)(grow + r) * DDIM + gcol] = f2bf(acc[m][n][r]);
        }
    }
}

// ---------------------------------------------------------------------------
// Kernel 4: LayerNorm + relu + residual epilogue. One wave per row. bf16 H in.
// ---------------------------------------------------------------------------
__global__ __launch_bounds__(256) void ln_kernel(
    const unsigned short* __restrict__ H, const float* __restrict__ src,
    const float* __restrict__ sent_mask,
    const float* __restrict__ ln_g, const float* __restrict__ ln_b,
    float* __restrict__ out)
{
    int lane = threadIdx.x & 63;
    int n    = blockIdx.x * 4 + (threadIdx.x >> 6);
    int j0   = lane * 8;

    uint4 hv = *(const uint4*)(H + (size_t)n * DDIM + j0);
    float hs[8]; unpack8(hv, hs);

    float sum = 0.f, sq = 0.f;
#pragma unroll
    for (int i = 0; i < 8; ++i) { sum += hs[i]; sq += hs[i] * hs[i]; }
#pragma unroll
    for (int o = 32; o > 0; o >>= 1) {
        sum += __shfl_xor(sum, o);
        sq  += __shfl_xor(sq, o);
    }
    float mu   = sum * (1.0f / 512.0f);
    float var  = sq * (1.0f / 512.0f) - mu * mu;
    float rstd = rsqrtf(var + 1e-5f);
    float sm   = sent_mask[n];

    float4 gg0 = *(const float4*)(ln_g + j0);
    float4 gg1 = *(const float4*)(ln_g + j0 + 4);
    float4 be0 = *(const float4*)(ln_b + j0);
    float4 be1 = *(const float4*)(ln_b + j0 + 4);
    const float* sr = src + (size_t)n * DDIM + j0;
    float4 s0 = *(const float4*)sr;
    float4 s1 = *(const float4*)(sr + 4);
    float gl[8] = {gg0.x, gg0.y, gg0.z, gg0.w, gg1.x, gg1.y, gg1.z, gg1.w};
    float bt[8] = {be0.x, be0.y, be0.z, be0.w, be1.x, be1.y, be1.z, be1.w};
    float srs[8] = {s0.x, s0.y, s0.z, s0.w, s1.x, s1.y, s1.z, s1.w};

    float o_[8];
#pragma unroll
    for (int i = 0; i < 8; ++i) {
        float v = (hs[i] - mu) * rstd * gl[i] + bt[i];
        v *= sm;
        v = fmaxf(v, 0.f);
        o_[i] = v * sm + srs[i];
    }
    float4 w0 = {o_[0], o_[1], o_[2], o_[3]};
    float4 w1 = {o_[4], o_[5], o_[6], o_[7]};
    float* op = out + (size_t)n * DDIM + j0;
    *(float4*)op = w0;
    *(float4*)(op + 4) = w1;
}

// ---------------------------------------------------------------------------
// Workspace layout (bytes):
//   xb    : 0           (8,388,608)   8192*512 bf16
//   Bt    : 8,388,608   (1,703,936)   4*52 tiles of 8 KB (tiled)
//   g_in  : 10,092,544  (32,768)
//   g_out : 10,125,312  (32,768)
//   g_loop: 10,158,080  (32,768)
//   At    : 10,190,848  (27,262,976)  64*52 tiles of 8 KB (tiled)
//   H     : 37,453,824  (8,388,608)   8192*512 bf16
// ---------------------------------------------------------------------------
extern "C" void kernel_launch(void* const* d_in, const int* in_sizes, int n_in,
                              void* d_out, int out_size, void* d_ws, size_t ws_size,
                              hipStream_t stream)
{
    const float* src       = (const float*)d_in[0];
    const int*   arc_in    = (const int*)d_in[1];
    const int*   lbl_in    = (const int*)d_in[2];
    const int*   arc_out   = (const int*)d_in[3];
    const int*   lbl_out   = (const int*)d_in[4];
    const float* mask_in   = (const float*)d_in[5];
    const float* mask_out  = (const float*)d_in[6];
    const float* mask_loop = (const float*)d_in[7];
    const float* sent_mask = (const float*)d_in[8];
    const float* V_in      = (const float*)d_in[9];
    const float* b_in      = (const float*)d_in[10];
    const float* Vg_in     = (const float*)d_in[11];
    const float* bg_in     = (const float*)d_in[12];
    const float* V_out     = (const float*)d_in[13];
    const float* b_out     = (const float*)d_in[14];
    const float* Vg_out    = (const float*)d_in[15];
    const float* bg_out    = (const float*)d_in[16];
    const float* W_loop    = (const float*)d_in[17];
    const float* Wg_loop   = (const float*)d_in[18];
    const float* ln_g      = (const float*)d_in[19];
    const float* ln_b      = (const float*)d_in[20];

    uint8_t* ws = (uint8_t*)d_ws;
    unsigned short* xb    = (unsigned short*)(ws);
    unsigned short* Bt    = (unsigned short*)(ws + 8388608);
    float*          g_in  = (float*)(ws + 10092544);
    float*          g_out = (float*)(ws + 10125312);
    float*          g_lp  = (float*)(ws + 10158080);
    unsigned short* At    = (unsigned short*)(ws + 10190848);
    unsigned short* H     = (unsigned short*)(ws + 37453824);

    prep_kernel<<<2256, 256, 0, stream>>>(src, Vg_in, Vg_out, Wg_loop,
                                          V_in, V_out, W_loop, b_in, b_out,
                                          xb, Bt, g_in, g_out, g_lp);
    aggx_kernel<<<1024, 512, 0, stream>>>(xb, g_in, g_out, g_lp,
                                          arc_in, lbl_in, arc_out, lbl_out,
                                          mask_in, mask_out, mask_loop,
                                          bg_in, bg_out, At);
    gemm6_kernel<<<256, 512, 0, stream>>>(At, Bt, H);
    ln_kernel<<<2048, 256, 0, stream>>>(H, src, sent_mask, ln_g, ln_b, (float*)d_out);
}

// Round 8
// 53.726 us; speedup vs baseline: 1.4889x; 1.4889x over previous
//
#include <hip/hip_runtime.h>
#include <cstdint>
#include <cstddef>

// Problem constants: B=16, S=512, DEG=8, D=512, L=64
#define DDIM   512
#define NNODES 8192      // B*S
#define NEDGE  65536     // B*S*DEG
#define PCOLS  1536      // 3*D
#define NKT    16        // K=512 / BK=32
#define TILE_SHORTS 4096 // one (128-row x 32-k) bf16 tile = [4 kb][128 row][8]

typedef __attribute__((ext_vector_type(8))) short bf16x8;
typedef __attribute__((ext_vector_type(4))) float f32x4;

#define AS1 __attribute__((address_space(1)))
#define AS3 __attribute__((address_space(3)))

static __device__ __forceinline__ unsigned short f2bf(float f) {
    unsigned u = __float_as_uint(f);
    u += 0x7FFFu + ((u >> 16) & 1u);   // round-to-nearest-even
    return (unsigned short)(u >> 16);
}

static __device__ __forceinline__ void unpack8(uint4 pv, float* pf) {
    const unsigned* pw = (const unsigned*)&pv;
    pf[0] = __uint_as_float(pw[0] << 16); pf[1] = __uint_as_float(pw[0] & 0xffff0000u);
    pf[2] = __uint_as_float(pw[1] << 16); pf[3] = __uint_as_float(pw[1] & 0xffff0000u);
    pf[4] = __uint_as_float(pw[2] << 16); pf[5] = __uint_as_float(pw[2] & 0xffff0000u);
    pf[6] = __uint_as_float(pw[3] << 16); pf[7] = __uint_as_float(pw[3] & 0xffff0000u);
}

// ---------------------------------------------------------------------------
// Kernel 1 (merged, 512 thr):
//   blocks [0,1024):       x -> tiled bf16 A-operand (xbt) + 3 gate dots
//   blocks [1024,1216):    Wcat^T tiled bf16 (192 transpose blocks)
//   blocks [1216,1248):    b_in/b_out -> bf16 row-major tables
// xbt tile(tm,kt) at ((tm*16+kt)*4096) shorts, [4 kb][128 row][8].
// 8 rows/block so the 8 rows sharing each 128B line are written in-block.
// ---------------------------------------------------------------------------
__global__ __launch_bounds__(512) void prep_kernel(
    const float* __restrict__ src,
    const float* __restrict__ vg_in, const float* __restrict__ vg_out,
    const float* __restrict__ vg_loop,
    const float* __restrict__ v_in, const float* __restrict__ v_out,
    const float* __restrict__ w_loop, const float* __restrict__ b_in,
    const float* __restrict__ b_out,
    unsigned short* __restrict__ xbt, unsigned short* __restrict__ wct,
    unsigned short* __restrict__ bb_in, unsigned short* __restrict__ bb_out,
    float* __restrict__ g_in, float* __restrict__ g_out, float* __restrict__ g_loop)
{
    __shared__ float tile[64][65];
    if (blockIdx.x < 1024) {
        int lane = threadIdx.x & 63;
        int row  = blockIdx.x * 8 + (threadIdx.x >> 6);
        int j0   = lane * 8;

        const float* x = src + (size_t)row * DDIM + j0;
        float4 x0 = *(const float4*)x;
        float4 x1 = *(const float4*)(x + 4);
        float xs[8] = {x0.x, x0.y, x0.z, x0.w, x1.x, x1.y, x1.z, x1.w};

        // tiled write: lane j -> kt = j>>2, kb = j&3
        alignas(16) unsigned short h[8];
#pragma unroll
        for (int i = 0; i < 8; ++i) h[i] = f2bf(xs[i]);
        int tm = row >> 7, rw = row & 127;
        size_t off = ((size_t)(tm * NKT + (lane >> 2))) * TILE_SHORTS
                   + ((size_t)(lane & 3) * 128 + rw) * 8;
        *(uint4*)(xbt + off) = *(const uint4*)h;

        float s0 = 0.f, s1 = 0.f, s2 = 0.f;
#pragma unroll
        for (int i = 0; i < 8; ++i) {
            s0 += xs[i] * vg_in[j0 + i];
            s1 += xs[i] * vg_out[j0 + i];
            s2 += xs[i] * vg_loop[j0 + i];
        }
#pragma unroll
        for (int o = 32; o > 0; o >>= 1) {
            s0 += __shfl_xor(s0, o);
            s1 += __shfl_xor(s1, o);
            s2 += __shfl_xor(s2, o);
        }
        if (lane == 0) { g_in[row] = s0; g_out[row] = s1; g_loop[row] = s2; }
    } else if (blockIdx.x < 1216) {
        int bb = blockIdx.x - 1024;       // 0..191
        int kc = bb / 24;                 // 0..7  (64-k chunk)
        int nt = bb % 24;                 // 0..23 (64-n chunk of Wcat)
        int k0 = kc * 64;

        const float* srcp; int nl0 = (nt & 7) * 64;
        if      (nt < 8)  srcp = v_in;
        else if (nt < 16) srcp = v_out;
        else              srcp = w_loop;

        int c  = threadIdx.x & 63;
        int rr = threadIdx.x >> 6;        // 0..7
#pragma unroll
        for (int i = 0; i < 8; ++i) {
            int kk = i * 8 + rr;
            tile[kk][c] = srcp[(size_t)(k0 + kk) * DDIM + nl0 + c];
        }
        __syncthreads();
        // write 512 chunks of 16B: idx = nn(0..63) x k8(0..7)
        int tn = nt >> 1;
        int nrbase = (nt & 1) * 64;
        int idx = threadIdx.x;
        int nn  = idx >> 3;
        int k8  = idx & 7;                // 8-elem k-group within 64
        int ktl = k8 >> 2;                // which 32-k tile (0/1)
        int kb  = k8 & 3;
        size_t tb = ((size_t)(tn * NKT + kc * 2 + ktl)) * TILE_SHORTS;
        alignas(16) unsigned short h[8];
#pragma unroll
        for (int e = 0; e < 8; ++e) h[e] = f2bf(tile[k8 * 8 + e][nn]);
        *(uint4*)(wct + tb + ((size_t)kb * 128 + nrbase + nn) * 8) = *(const uint4*)h;
    } else {
        // bias tables -> bf16 (2 x 64 x 512)
        int i = (blockIdx.x - 1216) * 512 + threadIdx.x;   // 0..16383
        int base = i * 4;
        int which = base >> 15;
        int off   = base & 32767;
        const float* s = which ? b_out : b_in;
        unsigned short* d = which ? bb_out : bb_in;
        float4 v = *(const float4*)(s + off);
        alignas(8) unsigned short h[4] = {f2bf(v.x), f2bf(v.y), f2bf(v.z), f2bf(v.w)};
        *(uint2*)(d + off) = *(const uint2*)h;
    }
}

// ---------------------------------------------------------------------------
// Kernel 2: GEMM  P[8192 x 1536](bf16,row-major) = x[8192x512] @ Wcat[512x1536]
// Pre-tiled operands (exact LDS image) -> fully coalesced staging.
// 128x128 tile, BK=32, 512 threads (8 waves 2m x 4n, each 64x32, 4x2 frags).
// 16 K-steps. Ring-3 LDS (48 KB) -> 3 blocks/CU, grid 768 fully resident.
// Counted vmcnt(4) (lookahead-2). XCD-affine swizzle.
// ---------------------------------------------------------------------------
__global__ __launch_bounds__(512, 6) void gemmp_kernel(
    const unsigned short* __restrict__ At,
    const unsigned short* __restrict__ Bt,
    unsigned short* __restrict__ P)
{
    __shared__ short lds_a[3][TILE_SHORTS];   // 3 bufs x 8 KB = 24 KB
    __shared__ short lds_b[3][TILE_SHORTS];   // 24 KB

    int tid  = threadIdx.x;
    int lane = tid & 63;
    int wid  = tid >> 6;                    // 0..7
    int bid  = blockIdx.x;
    int local = bid >> 3;                   // 0..95
    int tm    = (bid & 7) * 8 + local / 12; // 64 tm panels, 8 per XCD
    int tn    = local % 12;
    int row0 = tm * 128, col0 = tn * 128;
    int wm   = wid >> 2, wn = wid & 3;      // 2m x 4n waves, each 64 x 32
    int r16  = lane & 15, kq = lane >> 4;

    f32x4 acc[4][2];
#pragma unroll
    for (int m = 0; m < 4; ++m)
#pragma unroll
        for (int n = 0; n < 2; ++n) acc[m][n] = (f32x4){0.f, 0.f, 0.f, 0.f};

    const unsigned short* ga = At + (size_t)(tm * NKT) * TILE_SHORTS;
    const unsigned short* gb = Bt + (size_t)(tn * NKT) * TILE_SHORTS;

    auto stage = [&](int buf, int kt) {
        size_t kt8 = (size_t)kt * TILE_SHORTS;
        __builtin_amdgcn_global_load_lds(
            (const AS1 void*)(ga + kt8 + tid * 8),
            (AS3 void*)(&lds_a[buf][wid * 512]), 16, 0, 0);
        __builtin_amdgcn_global_load_lds(
            (const AS1 void*)(gb + kt8 + tid * 8),
            (AS3 void*)(&lds_b[buf][wid * 512]), 16, 0, 0);
    };

    auto compute = [&](int buf) {
        const short* la = lds_a[buf];
        const short* lb = lds_b[buf];
        bf16x8 af[4], bfr[2];
#pragma unroll
        for (int m = 0; m < 4; ++m)
            af[m] = *(const bf16x8*)(la + (kq * 128 + wm * 64 + m * 16 + r16) * 8);
#pragma unroll
        for (int n = 0; n < 2; ++n)
            bfr[n] = *(const bf16x8*)(lb + (kq * 128 + wn * 32 + n * 16 + r16) * 8);
#pragma unroll
        for (int m = 0; m < 4; ++m)
#pragma unroll
            for (int n = 0; n < 2; ++n)
                acc[m][n] = __builtin_amdgcn_mfma_f32_16x16x32_bf16(
                    af[m], bfr[n], acc[m][n], 0, 0, 0);
        __builtin_amdgcn_sched_barrier(0);
        __builtin_amdgcn_s_barrier();           // release buffer for restaging
    };

    // prologue: 2 stages in flight (4 loads/thread)
    stage(0, 0); stage(1, 1);

    // main loop: t = 0..13 stages t+2 = 2..15
    int bufc = 0;
    for (int t = 0; t < 14; ++t) {
        int bufs = bufc + 2; if (bufs >= 3) bufs -= 3;
        stage(bufs, t + 2);
        asm volatile("s_waitcnt vmcnt(4)" ::: "memory");   // stage t landed
        __builtin_amdgcn_sched_barrier(0);
        __builtin_amdgcn_s_barrier();
        __builtin_amdgcn_sched_barrier(0);
        compute(bufc);
        ++bufc; if (bufc == 3) bufc = 0;
    }
    // epilogue: t = 14, 15 (drain 2 -> 0)
    asm volatile("s_waitcnt vmcnt(2)" ::: "memory");
    __builtin_amdgcn_sched_barrier(0);
    __builtin_amdgcn_s_barrier();
    __builtin_amdgcn_sched_barrier(0);
    compute(bufc);                                  // t=14
    ++bufc; if (bufc == 3) bufc = 0;
    asm volatile("s_waitcnt vmcnt(0)" ::: "memory");
    __builtin_amdgcn_sched_barrier(0);
    __builtin_amdgcn_s_barrier();
    __builtin_amdgcn_sched_barrier(0);
    compute(bufc);                                  // t=15

    // C/D layout: col = lane&15, row = (lane>>4)*4 + reg; store bf16 row-major
#pragma unroll
    for (int m = 0; m < 4; ++m) {
        int grow = row0 + wm * 64 + m * 16 + kq * 4;
#pragma unroll
        for (int n = 0; n < 2; ++n) {
            int gcol = col0 + wn * 32 + n * 16 + r16;
#pragma unroll
            for (int r = 0; r < 4; ++r)
                P[(size_t)(grow + r) * PCOLS + gcol] = f2bf(acc[m][n][r]);
        }
    }
}

// ---------------------------------------------------------------------------
// Kernel 3: fused gather + bias + sigmoid-gate + LayerNorm + relu + residual.
// One wave per node (8 nodes / 512-thr block). Lane j owns cols 8j..8j+7.
// in:  P[sn, 0:512)   + bb_in[lb]
// out: P[sn, 512:1024)+ bb_out[lb]
// loop:P[n, 1024:1536)  (no bias)
// ---------------------------------------------------------------------------
__global__ __launch_bounds__(512) void aggf_kernel(
    const unsigned short* __restrict__ P,
    const float* __restrict__ g_in, const float* __restrict__ g_out,
    const float* __restrict__ g_loop,
    const int* __restrict__ arc_in, const int* __restrict__ lbl_in,
    const int* __restrict__ arc_out, const int* __restrict__ lbl_out,
    const float* __restrict__ mask_in, const float* __restrict__ mask_out,
    const float* __restrict__ mask_loop, const float* __restrict__ sent_mask,
    const unsigned short* __restrict__ bb_in, const unsigned short* __restrict__ bb_out,
    const float* __restrict__ bg_in, const float* __restrict__ bg_out,
    const float* __restrict__ ln_g, const float* __restrict__ ln_b,
    const float* __restrict__ src, float* __restrict__ out)
{
    int lane = threadIdx.x & 63;
    int n    = blockIdx.x * 8 + (threadIdx.x >> 6);
    int j0   = lane * 8;

    float acc[8] = {0,0,0,0,0,0,0,0};

#pragma unroll
    for (int k = 0; k < 8; ++k) {
        int e  = n * 8 + k;                    // wave-uniform
        float mk = mask_in[e];
        if (mk != 0.f) {                        // wave-uniform branch
            int sn = arc_in[e] * 512 + arc_in[NEDGE + e];
            int lb = lbl_in[e];
            float w = mk / (1.0f + __expf(-(g_in[sn] + bg_in[lb])));
            uint4 pv = *(const uint4*)(P + (size_t)sn * PCOLS + j0);
            uint4 bv = *(const uint4*)(bb_in + (size_t)lb * DDIM + j0);
            float pf[8], bf[8]; unpack8(pv, pf); unpack8(bv, bf);
#pragma unroll
            for (int i = 0; i < 8; ++i) acc[i] += w * (pf[i] + bf[i]);
        }
    }
#pragma unroll
    for (int k = 0; k < 8; ++k) {
        int e  = n * 8 + k;
        float mk = mask_out[e];
        if (mk != 0.f) {
            int sn = arc_out[e] * 512 + arc_out[NEDGE + e];
            int lb = lbl_out[e];
            float w = mk / (1.0f + __expf(-(g_out[sn] + bg_out[lb])));
            uint4 pv = *(const uint4*)(P + (size_t)sn * PCOLS + 512 + j0);
            uint4 bv = *(const uint4*)(bb_out + (size_t)lb * DDIM + j0);
            float pf[8], bf[8]; unpack8(pv, pf); unpack8(bv, bf);
#pragma unroll
            for (int i = 0; i < 8; ++i) acc[i] += w * (pf[i] + bf[i]);
        }
    }
    {
        float wl = mask_loop[n] / (1.0f + __expf(-g_loop[n]));
        uint4 pv = *(const uint4*)(P + (size_t)n * PCOLS + 1024 + j0);
        float pf[8]; unpack8(pv, pf);
#pragma unroll
        for (int i = 0; i < 8; ++i) acc[i] += wl * pf[i];
    }

    // LayerNorm over D=512 within the wave
    float sum = 0.f, sq = 0.f;
#pragma unroll
    for (int i = 0; i < 8; ++i) { sum += acc[i]; sq += acc[i] * acc[i]; }
#pragma unroll
    for (int o = 32; o > 0; o >>= 1) {
        sum += __shfl_xor(sum, o);
        sq  += __shfl_xor(sq, o);
    }
    float mu   = sum * (1.0f / 512.0f);
    float var  = sq * (1.0f / 512.0f) - mu * mu;
    float rstd = rsqrtf(var + 1e-5f);
    float sm   = sent_mask[n];

    float4 gg0 = *(const float4*)(ln_g + j0);
    float4 gg1 = *(const float4*)(ln_g + j0 + 4);
    float4 be0 = *(const float4*)(ln_b + j0);
    float4 be1 = *(const float4*)(ln_b + j0 + 4);
    const float* sr = src + (size_t)n * DDIM + j0;
    float4 s0 = *(const float4*)sr;
    float4 s1 = *(const float4*)(sr + 4);
    float gl[8] = {gg0.x, gg0.y, gg0.z, gg0.w, gg1.x, gg1.y, gg1.z, gg1.w};
    float bt[8] = {be0.x, be0.y, be0.z, be0.w, be1.x, be1.y, be1.z, be1.w};
    float srs[8] = {s0.x, s0.y, s0.z, s0.w, s1.x, s1.y, s1.z, s1.w};

    float o_[8];
#pragma unroll
    for (int i = 0; i < 8; ++i) {
        float v = (acc[i] - mu) * rstd * gl[i] + bt[i];
        v *= sm;
        v = fmaxf(v, 0.f);
        o_[i] = v * sm + srs[i];
    }
    float4 w0 = {o_[0], o_[1], o_[2], o_[3]};
    float4 w1 = {o_[4], o_[5], o_[6], o_[7]};
    float* op = out + (size_t)n * DDIM + j0;
    *(float4*)op = w0;
    *(float4*)(op + 4) = w1;
}

// ---------------------------------------------------------------------------
// Workspace layout (bytes):
//   xbt   : 0           (8,388,608)   64*16 tiles of 8 KB (tiled A)
//   wct   : 8,388,608   (1,572,864)   12*16 tiles of 8 KB (tiled Wcat^T)
//   bb_in : 9,961,472   (65,536)      64x512 bf16
//   bb_out: 10,027,008  (65,536)
//   g_in  : 10,092,544  (32,768)
//   g_out : 10,125,312  (32,768)
//   g_loop: 10,158,080  (32,768)
//   P     : 10,190,848  (25,165,824)  8192x1536 bf16 row-major
// ---------------------------------------------------------------------------
extern "C" void kernel_launch(void* const* d_in, const int* in_sizes, int n_in,
                              void* d_out, int out_size, void* d_ws, size_t ws_size,
                              hipStream_t stream)
{
    const float* src       = (const float*)d_in[0];
    const int*   arc_in    = (const int*)d_in[1];
    const int*   lbl_in    = (const int*)d_in[2];
    const int*   arc_out   = (const int*)d_in[3];
    const int*   lbl_out   = (const int*)d_in[4];
    const float* mask_in   = (const float*)d_in[5];
    const float* mask_out  = (const float*)d_in[6];
    const float* mask_loop = (const float*)d_in[7];
    const float* sent_mask = (const float*)d_in[8];
    const float* V_in      = (const float*)d_in[9];
    const float* b_in      = (const float*)d_in[10];
    const float* Vg_in     = (const float*)d_in[11];
    const float* bg_in     = (const float*)d_in[12];
    const float* V_out     = (const float*)d_in[13];
    const float* b_out     = (const float*)d_in[14];
    const float* Vg_out    = (const float*)d_in[15];
    const float* bg_out    = (const float*)d_in[16];
    const float* W_loop    = (const float*)d_in[17];
    const float* Wg_loop   = (const float*)d_in[18];
    const float* ln_g      = (const float*)d_in[19];
    const float* ln_b      = (const float*)d_in[20];

    uint8_t* ws = (uint8_t*)d_ws;
    unsigned short* xbt   = (unsigned short*)(ws);
    unsigned short* wct   = (unsigned short*)(ws + 8388608);
    unsigned short* bb_in = (unsigned short*)(ws + 9961472);
    unsigned short* bb_out= (unsigned short*)(ws + 10027008);
    float*          g_in  = (float*)(ws + 10092544);
    float*          g_out = (float*)(ws + 10125312);
    float*          g_lp  = (float*)(ws + 10158080);
    unsigned short* P     = (unsigned short*)(ws + 10190848);

    prep_kernel<<<1248, 512, 0, stream>>>(src, Vg_in, Vg_out, Wg_loop,
                                          V_in, V_out, W_loop, b_in, b_out,
                                          xbt, wct, bb_in, bb_out,
                                          g_in, g_out, g_lp);
    gemmp_kernel<<<768, 512, 0, stream>>>(xbt, wct, P);
    aggf_kernel<<<1024, 512, 0, stream>>>(P, g_in, g_out, g_lp,
                                          arc_in, lbl_in, arc_out, lbl_out,
                                          mask_in, mask_out, mask_loop, sent_mask,
                                          bb_in, bb_out, bg_in, bg_out,
                                          ln_g, ln_b, src, (float*)d_out);
}